// Round 1
// baseline (1215.436 us; speedup 1.0000x reference)
//
#include <hip/hip_runtime.h>
#include <hip/hip_bf16.h>

#define N_   4
#define CIN  1024
#define H_   56
#define W_   56
#define HW   3136
#define CB   256
#define KK   9
#define OFFC 18

// ---------------------------------------------------------------------------
// Kernel: transpose w2 (o,c,k) -> w2t (k,c,o)  so GEMM-B loads are coalesced
// ---------------------------------------------------------------------------
__global__ void __launch_bounds__(256) transpose_w2_kernel(
    const float* __restrict__ w2, float* __restrict__ w2t)
{
    int e = blockIdx.x * 256 + threadIdx.x;      // 9*256*256 = 589824 total
    if (e >= KK * CB * CB) return;
    int o = e & 255;
    int c = (e >> 8) & 255;
    int k = e >> 16;
    w2t[e] = w2[o * (CB * KK) + c * KK + k];     // write coalesced
}

// ---------------------------------------------------------------------------
// Kernel: 1x1 conv as GEMM:  C[m,p] = act( bias[m] + sum_k Wg[m,k]*Xin[k,p] )
// 64x64 tile, TK=16, 256 threads, 4x4 accs/thread, float4 LDS reads.
// ---------------------------------------------------------------------------
template <bool RELU, bool RESID>
__global__ void __launch_bounds__(256) conv1x1_kernel(
    const float* __restrict__ Wg,   // [M, Kdim]
    const float* __restrict__ Xin,  // [n][Kdim][HW]
    const float* __restrict__ bias, // [M]
    const float* __restrict__ resid,// [n][M][HW] or null
    float* __restrict__ Cout,       // [n][M][HW]
    int M, int Kdim)
{
    __shared__ float Ws[16][64];
    __shared__ float Bs[16][64];

    const int n     = blockIdx.z;
    const int mBase = blockIdx.y * 64;
    const int pBase = blockIdx.x * 64;
    const int tid   = threadIdx.x;
    const int tx    = tid & 15;   // p group
    const int ty    = tid >> 4;   // m group

    const float* Xn = Xin + (size_t)n * Kdim * HW;

    float acc[4][4];
#pragma unroll
    for (int i = 0; i < 4; ++i)
#pragma unroll
        for (int j = 0; j < 4; ++j) acc[i][j] = 0.f;

    for (int k0 = 0; k0 < Kdim; k0 += 16) {
        // W tile: 64 m x 16 k. Thread loads float4 along k, scatters transposed.
        {
            int m  = tid >> 2;
            int ks = (tid & 3) * 4;
            float4 wv = *reinterpret_cast<const float4*>(
                &Wg[(size_t)(mBase + m) * Kdim + k0 + ks]);
            Ws[ks + 0][m] = wv.x;
            Ws[ks + 1][m] = wv.y;
            Ws[ks + 2][m] = wv.z;
            Ws[ks + 3][m] = wv.w;
        }
        // B tile: 16 k x 64 p, coalesced float4.
        {
            int kk = tid >> 4;
            int p  = (tid & 15) * 4;
            float4 bv = *reinterpret_cast<const float4*>(
                &Xn[(size_t)(k0 + kk) * HW + pBase + p]);
            *reinterpret_cast<float4*>(&Bs[kk][p]) = bv;
        }
        __syncthreads();
#pragma unroll
        for (int kk = 0; kk < 16; ++kk) {
            float4 av = *reinterpret_cast<const float4*>(&Ws[kk][ty * 4]);
            float4 bv = *reinterpret_cast<const float4*>(&Bs[kk][tx * 4]);
            float a[4] = {av.x, av.y, av.z, av.w};
            float b[4] = {bv.x, bv.y, bv.z, bv.w};
#pragma unroll
            for (int i = 0; i < 4; ++i)
#pragma unroll
                for (int j = 0; j < 4; ++j) acc[i][j] += a[i] * b[j];
        }
        __syncthreads();
    }

    // epilogue
#pragma unroll
    for (int i = 0; i < 4; ++i) {
        int m = mBase + ty * 4 + i;
        float bv = bias[m];
        int p = pBase + tx * 4;
        size_t base = ((size_t)n * M + m) * HW + p;
        float4 v;
        float out[4];
#pragma unroll
        for (int j = 0; j < 4; ++j) out[j] = acc[i][j] + bv;
        if (RESID) {
            float4 rv = *reinterpret_cast<const float4*>(&resid[base]);
            out[0] += rv.x; out[1] += rv.y; out[2] += rv.z; out[3] += rv.w;
        }
        if (RELU) {
#pragma unroll
            for (int j = 0; j < 4; ++j) out[j] = fmaxf(out[j], 0.f);
        }
        v.x = out[0]; v.y = out[1]; v.z = out[2]; v.w = out[3];
        *reinterpret_cast<float4*>(&Cout[base]) = v;
    }
}

// ---------------------------------------------------------------------------
// Kernel: offset conv 3x3 SAME: off[n,c,h,w], c in [0,18)
// One thread per output element; ci-loop over 256 channels.
// ---------------------------------------------------------------------------
__global__ void __launch_bounds__(256) offset_conv_kernel(
    const float* __restrict__ r, const float* __restrict__ w_off,
    const float* __restrict__ b_off, float* __restrict__ off)
{
    int id = blockIdx.x * 256 + threadIdx.x;
    if (id >= N_ * OFFC * HW) return;
    int p = id % HW;
    int c = (id / HW) % OFFC;
    int n = id / (OFFC * HW);
    int h = p / W_, w = p % W_;

    float acc = b_off[c];
    const float* rn = r + (size_t)n * CB * HW;
    const float* wc = w_off + (size_t)c * CB * KK;

    for (int ci = 0; ci < CB; ++ci) {
        const float* rp = rn + ci * HW;
        const float* wp = wc + ci * KK;
#pragma unroll
        for (int ki = 0; ki < 3; ++ki) {
            int y = h + ki - 1;
            if (y < 0 || y >= H_) continue;
#pragma unroll
            for (int kj = 0; kj < 3; ++kj) {
                int x = w + kj - 1;
                if (x < 0 || x >= W_) continue;
                acc += rp[y * W_ + x] * wp[ki * 3 + kj];
            }
        }
    }
    off[id] = acc;
}

// ---------------------------------------------------------------------------
// Kernel: fused deformable sampling + GEMM + bias + relu
// Block: 256 threads, handles (n, 32 positions, 128 of 256 outputs).
// Grid: (HW/32, 2, N)
// ---------------------------------------------------------------------------
#define TP 32
__global__ void __launch_bounds__(256) deform_gemm_kernel(
    const float* __restrict__ r,     // [n][CB][HW]
    const float* __restrict__ off,   // [n][18][HW]
    const float* __restrict__ w2t,   // [k][c][o]  (9,256,256)
    const float* __restrict__ b2,    // [CB]
    float* __restrict__ r2)          // [n][CB][HW]
{
    __shared__ float offs[OFFC][TP];     // 2.25 KB
    __shared__ int   cidx[KK][TP][4];    // 4.5 KB
    __shared__ float cwgt[KK][TP][4];    // 4.5 KB
    __shared__ float As[32][TP];         // 4 KB
    __shared__ float Wsh[32][128];       // 16 KB

    const int tid   = threadIdx.x;
    const int pBase = blockIdx.x * TP;
    const int oBase = blockIdx.y * 128;
    const int n     = blockIdx.z;

    // stage offsets for this position tile
    for (int e = tid; e < OFFC * TP; e += 256) {
        int ch = e / TP, p = e % TP;
        offs[ch][p] = off[((size_t)n * OFFC + ch) * HW + pBase + p];
    }
    __syncthreads();

    // precompute bilinear corners (idx, weight) for each (k, p)
    for (int e = tid; e < KK * TP; e += 256) {
        int k = e / TP, p = e % TP;
        int pos = pBase + p;
        int h = pos / W_, w = pos % W_;
        float dy = offs[2 * k][p];
        float dx = offs[2 * k + 1][p];
        float ys = (float)(h + (k / 3) - 1) + dy;
        float xs = (float)(w + (k % 3) - 1) + dx;
        float y0f = floorf(ys), x0f = floorf(xs);
        float wy1 = ys - y0f, wy0 = 1.f - wy1;
        float wx1 = xs - x0f, wx0 = 1.f - wx1;
        int y0 = (int)y0f, x0 = (int)x0f;
        int yy[2] = {y0, y0 + 1};
        int xx[2] = {x0, x0 + 1};
        float wy[2] = {wy0, wy1};
        float wx[2] = {wx0, wx1};
#pragma unroll
        for (int u = 0; u < 2; ++u) {
#pragma unroll
            for (int v = 0; v < 2; ++v) {
                bool valid = (yy[u] >= 0) && (yy[u] <= H_ - 1) &&
                             (xx[v] >= 0) && (xx[v] <= W_ - 1);
                int yc = min(max(yy[u], 0), H_ - 1);
                int xc = min(max(xx[v], 0), W_ - 1);
                cidx[k][p][u * 2 + v] = yc * W_ + xc;
                cwgt[k][p][u * 2 + v] = valid ? (wy[u] * wx[v]) : 0.f;
            }
        }
    }
    __syncthreads();

    const int tx = tid & 7;    // p group: p = tx*4 + j
    const int to = tid >> 3;   // o group: o = to*4 + i

    float acc[4][4];
#pragma unroll
    for (int i = 0; i < 4; ++i)
#pragma unroll
        for (int j = 0; j < 4; ++j) acc[i][j] = 0.f;

    const float* rn = r + (size_t)n * CB * HW;

    for (int k = 0; k < KK; ++k) {
        for (int cb = 0; cb < CB; cb += 32) {
            // build sampled A tile: As[c][p]
#pragma unroll
            for (int ii = 0; ii < 4; ++ii) {
                int e = tid + 256 * ii;
                int c = e >> 5, p = e & 31;
                const float* base = rn + (size_t)(cb + c) * HW;
                int4   id4 = *reinterpret_cast<const int4*>(&cidx[k][p][0]);
                float4 wv4 = *reinterpret_cast<const float4*>(&cwgt[k][p][0]);
                float v = wv4.x * base[id4.x] + wv4.y * base[id4.y] +
                          wv4.z * base[id4.z] + wv4.w * base[id4.w];
                As[c][p] = v;
            }
            // stage W tile: Wsh[c][o]  (coalesced from w2t)
#pragma unroll
            for (int ii = 0; ii < 16; ++ii) {
                int e = tid + 256 * ii;
                int c = e >> 7, o = e & 127;
                Wsh[c][o] = w2t[(size_t)k * CB * CB + (size_t)(cb + c) * CB +
                                oBase + o];
            }
            __syncthreads();
#pragma unroll 8
            for (int c = 0; c < 32; ++c) {
                float4 av = *reinterpret_cast<const float4*>(&Wsh[c][to * 4]);
                float4 bv = *reinterpret_cast<const float4*>(&As[c][tx * 4]);
                float a[4] = {av.x, av.y, av.z, av.w};
                float b[4] = {bv.x, bv.y, bv.z, bv.w};
#pragma unroll
                for (int i = 0; i < 4; ++i)
#pragma unroll
                    for (int j = 0; j < 4; ++j) acc[i][j] += a[i] * b[j];
            }
            __syncthreads();
        }
    }

    // epilogue: bias + relu, store r2
#pragma unroll
    for (int i = 0; i < 4; ++i) {
        int o = oBase + to * 4 + i;
        float bv = b2[o];
        int p = pBase + tx * 4;
        float4 v;
        v.x = fmaxf(acc[i][0] + bv, 0.f);
        v.y = fmaxf(acc[i][1] + bv, 0.f);
        v.z = fmaxf(acc[i][2] + bv, 0.f);
        v.w = fmaxf(acc[i][3] + bv, 0.f);
        *reinterpret_cast<float4*>(&r2[((size_t)n * CB + o) * HW + p]) = v;
    }
}

// ---------------------------------------------------------------------------
// kernel_launch
// ---------------------------------------------------------------------------
extern "C" void kernel_launch(void* const* d_in, const int* in_sizes, int n_in,
                              void* d_out, int out_size, void* d_ws, size_t ws_size,
                              hipStream_t stream)
{
    const float* x     = (const float*)d_in[0];
    const float* w1    = (const float*)d_in[1];
    const float* b1    = (const float*)d_in[2];
    const float* w_off = (const float*)d_in[3];
    const float* b_off = (const float*)d_in[4];
    const float* w2    = (const float*)d_in[5];
    const float* b2    = (const float*)d_in[6];
    const float* w3    = (const float*)d_in[7];
    const float* b3    = (const float*)d_in[8];
    float* out = (float*)d_out;

    float* ws  = (float*)d_ws;
    float* r   = ws;                             // N*CB*HW   = 3,211,264
    float* r2  = r + (size_t)N_ * CB * HW;       // N*CB*HW   = 3,211,264
    float* off = r2 + (size_t)N_ * CB * HW;      // N*18*HW   =   225,792
    float* w2t = off + (size_t)N_ * OFFC * HW;   // 9*256*256 =   589,824

    // 1) transpose w2 -> w2t[k][c][o]
    {
        int total = KK * CB * CB;
        transpose_w2_kernel<<<(total + 255) / 256, 256, 0, stream>>>(w2, w2t);
    }
    // 2) r = relu(x * w1 + b1)   GEMM M=256, K=1024
    {
        dim3 grid(HW / 64, CB / 64, N_);
        conv1x1_kernel<true, false><<<grid, 256, 0, stream>>>(
            w1, x, b1, nullptr, r, CB, CIN);
    }
    // 3) off = conv3x3(r, w_off) + b_off
    {
        int total = N_ * OFFC * HW;
        offset_conv_kernel<<<(total + 255) / 256, 256, 0, stream>>>(
            r, w_off, b_off, off);
    }
    // 4) r2 = relu(deform_gemm(r, off, w2) + b2)
    {
        dim3 grid(HW / TP, CB / 128, N_);
        deform_gemm_kernel<<<grid, 256, 0, stream>>>(r, off, w2t, b2, r2);
    }
    // 5) out = relu(x + r2 * w3 + b3)   GEMM M=1024, K=256, residual
    {
        dim3 grid(HW / 64, CIN / 64, N_);
        conv1x1_kernel<true, true><<<grid, 256, 0, stream>>>(
            w3, r2, b3, x, out, CIN, CB);
    }
}

// Round 2
// 766.297 us; speedup vs baseline: 1.5861x; 1.5861x over previous
//
#include <hip/hip_runtime.h>
#include <hip/hip_bf16.h>

#define N_   4
#define CIN  1024
#define H_   56
#define W_   56
#define HW   3136
#define CB   256
#define KK   9
#define OFFC 18

typedef __attribute__((ext_vector_type(8))) short short8;
typedef __attribute__((ext_vector_type(4))) short short4v;
typedef __attribute__((ext_vector_type(4))) float float4v;
typedef unsigned short ushort_t;

// fp32 -> bf16 round-to-nearest-even
__device__ inline ushort_t bf16_rne(float f) {
    unsigned int u = __float_as_uint(f);
    unsigned int r = (u + 0x7FFFu + ((u >> 16) & 1u)) >> 16;
    return (ushort_t)r;
}
__device__ inline void split_bf16(float f, ushort_t& hi, ushort_t& lo) {
    ushort_t h = bf16_rne(f);
    float hf = __uint_as_float(((unsigned int)h) << 16);
    hi = h;
    lo = bf16_rne(f - hf);
}
__device__ inline short8 ld_frag_lds(const ushort_t* base) {
    short4v a = *(const short4v*)base;
    short4v b = *(const short4v*)(base + 4);
    return __builtin_shufflevector(a, b, 0, 1, 2, 3, 4, 5, 6, 7);
}

// ---------------------------------------------------------------------------
// Pack weights into split bf16 hi/lo planes.
// w1 [256][1024]      -> w1p [o][2][1024]
// w2 [256][256][9]    -> w2p [k][o][2][256]
// w3 [1024][256]      -> w3p [o][2][256]
// ---------------------------------------------------------------------------
__global__ void __launch_bounds__(256) pack_weights_kernel(
    const float* __restrict__ w1, const float* __restrict__ w2,
    const float* __restrict__ w3,
    ushort_t* __restrict__ w1p, ushort_t* __restrict__ w2p,
    ushort_t* __restrict__ w3p)
{
    int e = blockIdx.x * 256 + threadIdx.x;
    if (e < 256 * 1024) {
        int o = e >> 10, k = e & 1023;
        ushort_t hi, lo; split_bf16(w1[e], hi, lo);
        w1p[(size_t)(o * 2 + 0) * 1024 + k] = hi;
        w1p[(size_t)(o * 2 + 1) * 1024 + k] = lo;
        return;
    }
    e -= 256 * 1024;
    if (e < 256 * 256 * 9) {
        int o = e / 2304; int rem = e % 2304; int c = rem / 9; int k = rem % 9;
        ushort_t hi, lo; split_bf16(w2[e], hi, lo);
        size_t base = ((size_t)(k * 256 + o) * 2) * 256 + c;
        w2p[base] = hi; w2p[base + 256] = lo;
        return;
    }
    e -= 256 * 256 * 9;
    if (e < 1024 * 256) {
        int o = e >> 8, k = e & 255;
        ushort_t hi, lo; split_bf16(w3[e], hi, lo);
        w3p[(size_t)(o * 2 + 0) * 256 + k] = hi;
        w3p[(size_t)(o * 2 + 1) * 256 + k] = lo;
    }
}

// ---------------------------------------------------------------------------
// 1x1 conv via MFMA, split-bf16 3-pass.
// C[m,p] = act(bias[m] + sum_k W[m,k] X[k,p] (+resid))
// Block: 256 thr = 4 waves, BM=256 (wave: 64 m), BN=64, BK=32.
// A-frags direct from global (packed hi/lo), B staged fp32->split->LDS.
// ---------------------------------------------------------------------------
template <bool RELU, bool RESID>
__global__ void __launch_bounds__(256, 2) conv1x1_mfma_kernel(
    const ushort_t* __restrict__ Wp,   // [M][2][Kdim]
    const float* __restrict__ Xin,     // [n][Kdim][HW]
    const float* __restrict__ bias,    // [M]
    const float* __restrict__ resid,   // [n][M][HW] or null
    float* __restrict__ Cout,          // [n][M][HW]
    int M, int Kdim)
{
    __shared__ ushort_t Bs[2][64][36];   // [plane][p][k], pad 36

    const int tid  = threadIdx.x;
    const int wave = tid >> 6;
    const int lane = tid & 63;
    const int l15  = lane & 15;
    const int quad = lane >> 4;
    const int pBase = blockIdx.x * 64;
    const int mBase = blockIdx.y * 256 + wave * 64;
    const int n     = blockIdx.z;
    const float* Xn = Xin + (size_t)n * Kdim * HW;

    float4v acc[4][4];
#pragma unroll
    for (int i = 0; i < 4; ++i)
#pragma unroll
        for (int j = 0; j < 4; ++j) acc[i][j] = (float4v)(0.f);

    const int kk = tid >> 3;          // 0..31
    const int pq = (tid & 7) * 8;     // 0..56

    for (int k0 = 0; k0 < Kdim; k0 += 32) {
        const float* src = &Xn[(size_t)(k0 + kk) * HW + pBase + pq];
        float4 v0 = *reinterpret_cast<const float4*>(src);
        float4 v1 = *reinterpret_cast<const float4*>(src + 4);
        __syncthreads();   // previous iter's Bs reads are done
        float vs[8] = {v0.x, v0.y, v0.z, v0.w, v1.x, v1.y, v1.z, v1.w};
#pragma unroll
        for (int j = 0; j < 8; ++j) {
            ushort_t hi, lo; split_bf16(vs[j], hi, lo);
            Bs[0][pq + j][kk] = hi;
            Bs[1][pq + j][kk] = lo;
        }
        __syncthreads();

        short8 ah[4], al[4];
#pragma unroll
        for (int mt = 0; mt < 4; ++mt) {
            const ushort_t* arow = Wp +
                ((size_t)(mBase + mt * 16 + l15) * 2) * Kdim + k0 + quad * 8;
            ah[mt] = *(const short8*)(arow);
            al[mt] = *(const short8*)(arow + Kdim);
        }
        short8 bh[4], bl[4];
#pragma unroll
        for (int nt = 0; nt < 4; ++nt) {
            bh[nt] = ld_frag_lds(&Bs[0][nt * 16 + l15][quad * 8]);
            bl[nt] = ld_frag_lds(&Bs[1][nt * 16 + l15][quad * 8]);
        }
#pragma unroll
        for (int mt = 0; mt < 4; ++mt)
#pragma unroll
            for (int nt = 0; nt < 4; ++nt) {
                acc[mt][nt] = __builtin_amdgcn_mfma_f32_16x16x32_bf16(
                    ah[mt], bh[nt], acc[mt][nt], 0, 0, 0);
                acc[mt][nt] = __builtin_amdgcn_mfma_f32_16x16x32_bf16(
                    ah[mt], bl[nt], acc[mt][nt], 0, 0, 0);
                acc[mt][nt] = __builtin_amdgcn_mfma_f32_16x16x32_bf16(
                    al[mt], bh[nt], acc[mt][nt], 0, 0, 0);
            }
    }

#pragma unroll
    for (int mt = 0; mt < 4; ++mt)
#pragma unroll
        for (int rr = 0; rr < 4; ++rr) {
            int row = mBase + mt * 16 + quad * 4 + rr;
            float bv = bias[row];
#pragma unroll
            for (int nt = 0; nt < 4; ++nt) {
                int col = pBase + nt * 16 + l15;
                size_t idx = ((size_t)n * M + row) * HW + col;
                float v = acc[mt][nt][rr] + bv;
                if (RESID) v += resid[idx];
                if (RELU)  v = fmaxf(v, 0.f);
                Cout[idx] = v;
            }
        }
}

// ---------------------------------------------------------------------------
// Offset conv 3x3 SAME (18 out channels) — unchanged fp32 direct.
// ---------------------------------------------------------------------------
__global__ void __launch_bounds__(256) offset_conv_kernel(
    const float* __restrict__ r, const float* __restrict__ w_off,
    const float* __restrict__ b_off, float* __restrict__ off)
{
    int id = blockIdx.x * 256 + threadIdx.x;
    if (id >= N_ * OFFC * HW) return;
    int p = id % HW;
    int c = (id / HW) % OFFC;
    int n = id / (OFFC * HW);
    int h = p / W_, w = p % W_;

    float acc = b_off[c];
    const float* rn = r + (size_t)n * CB * HW;
    const float* wc = w_off + (size_t)c * CB * KK;

    for (int ci = 0; ci < CB; ++ci) {
        const float* rp = rn + ci * HW;
        const float* wp = wc + ci * KK;
#pragma unroll
        for (int ki = 0; ki < 3; ++ki) {
            int y = h + ki - 1;
            if (y < 0 || y >= H_) continue;
#pragma unroll
            for (int kj = 0; kj < 3; ++kj) {
                int x = w + kj - 1;
                if (x < 0 || x >= W_) continue;
                acc += rp[y * W_ + x] * wp[ki * 3 + kj];
            }
        }
    }
    off[id] = acc;
}

// ---------------------------------------------------------------------------
// Deformable conv via MFMA, split-bf16 3-pass, LDS window staging.
// Block: 256 thr = 4 waves. One block per (row h, o-half, n).
// BM=128 (wave: 32 m), BN=64 (56 real + 8 pad), reduction 2304 in chunks:
// outer c-blocks of 32 channels (window staged once), inner 9 taps.
// ---------------------------------------------------------------------------
__global__ void __launch_bounds__(256, 2) deform_mfma_kernel(
    const float* __restrict__ r,      // [n][CB][HW]
    const float* __restrict__ off,    // [n][18][HW]
    const ushort_t* __restrict__ w2p, // [9][256][2][256]
    const float* __restrict__ b2,
    float* __restrict__ r2)           // [n][CB][HW]
{
    __shared__ float    win[32][280];        // 5 rows x 56 cols per channel
    __shared__ ushort_t Bs[2][64][36];
    __shared__ short    widx[KK][56][4];
    __shared__ float    wwgt[KK][56][4];
    __shared__ unsigned char fastf[KK][56];

    const int tid   = threadIdx.x;
    const int h     = blockIdx.x;           // 0..55
    const int oBase = blockIdx.y * 128;
    const int n     = blockIdx.z;
    const float* rn   = r + (size_t)n * CB * HW;
    const float* offn = off + (size_t)n * OFFC * HW;

    // ---- per-(tap, position) bilinear metadata, window-relative ----
    for (int e = tid; e < KK * 56; e += 256) {
        int k = e / 56, p = e % 56;
        float dy = offn[(size_t)(2 * k) * HW + h * W_ + p];
        float dx = offn[(size_t)(2 * k + 1) * HW + h * W_ + p];
        float ys = (float)(h + (k / 3) - 1) + dy;
        float xs = (float)(p + (k % 3) - 1) + dx;
        float y0f = floorf(ys), x0f = floorf(xs);
        int y0 = (int)y0f, x0 = (int)x0f;
        float wy1 = ys - y0f, wy0 = 1.f - wy1;
        float wx1 = xs - x0f, wx0 = 1.f - wx1;
        bool fast = true;
#pragma unroll
        for (int u = 0; u < 2; ++u)
#pragma unroll
            for (int vv = 0; vv < 2; ++vv) {
                int yy = y0 + u, xx = x0 + vv;
                bool valid = (yy >= 0) && (yy <= 55) && (xx >= 0) && (xx <= 55);
                float wgt = valid ? (u ? wy1 : wy0) * (vv ? wx1 : wx0) : 0.f;
                int slot = yy - (h - 2);
                if (wgt != 0.f && (slot < 0 || slot > 4)) fast = false;
                int slotc = min(max(slot, 0), 4);
                int xc = min(max(xx, 0), 55);
                widx[k][p][u * 2 + vv] = (short)(slotc * 56 + xc);
                wwgt[k][p][u * 2 + vv] = wgt;
            }
        fastf[k][p] = fast ? 1 : 0;
    }

    const int wave = tid >> 6;
    const int lane = tid & 63;
    const int l15  = lane & 15;
    const int quad = lane >> 4;
    const int mW   = oBase + wave * 32;

    float4v acc[2][4];
#pragma unroll
    for (int i = 0; i < 2; ++i)
#pragma unroll
        for (int j = 0; j < 4; ++j) acc[i][j] = (float4v)(0.f);

    for (int cb = 0; cb < CB; cb += 32) {
        __syncthreads();  // prev Bs/win reads done; meta ready on first iter
        // ---- stage window: 32 ch x 5 rows x 56 cols ----
        for (int f = tid; f < 2240; f += 256) {
            int c = f / 70;
            int remf = f % 70;
            int row = remf / 14;
            int x4 = (remf % 14) * 4;
            int rowg = min(max(h - 2 + row, 0), 55);
            const float4* src = reinterpret_cast<const float4*>(
                &rn[(size_t)(cb + c) * HW + rowg * W_ + x4]);
            *reinterpret_cast<float4*>(&win[c][row * 56 + x4]) = *src;
        }
        __syncthreads();

        for (int k = 0; k < KK; ++k) {
            if (k) __syncthreads();  // prev tap's Bs reads done
            // ---- build B tile: samples for 32 ch x 64 p ----
#pragma unroll
            for (int ii = 0; ii < 8; ++ii) {
                int e = tid + 256 * ii;
                int c = e >> 6, p = e & 63;
                float sv = 0.f;
                if (p < 56) {
                    if (fastf[k][p]) {
                        const float* wc = win[c];
                        short4v id4 = *(const short4v*)&widx[k][p][0];
                        float4 w4 = *reinterpret_cast<const float4*>(&wwgt[k][p][0]);
                        sv = w4.x * wc[id4.x] + w4.y * wc[id4.y] +
                             w4.z * wc[id4.z] + w4.w * wc[id4.w];
                    } else {
                        // rare fallback: recompute, gather from global
                        float dy = offn[(size_t)(2 * k) * HW + h * W_ + p];
                        float dx = offn[(size_t)(2 * k + 1) * HW + h * W_ + p];
                        float ys = (float)(h + (k / 3) - 1) + dy;
                        float xs = (float)(p + (k % 3) - 1) + dx;
                        float y0f = floorf(ys), x0f = floorf(xs);
                        int y0 = (int)y0f, x0 = (int)x0f;
                        float wy1 = ys - y0f, wy0 = 1.f - wy1;
                        float wx1 = xs - x0f, wx0 = 1.f - wx1;
                        const float* rc = rn + (size_t)(cb + c) * HW;
#pragma unroll
                        for (int u = 0; u < 2; ++u)
#pragma unroll
                            for (int vv = 0; vv < 2; ++vv) {
                                int yy = y0 + u, xx = x0 + vv;
                                if (yy >= 0 && yy <= 55 && xx >= 0 && xx <= 55) {
                                    float wgt = (u ? wy1 : wy0) * (vv ? wx1 : wx0);
                                    sv += wgt * rc[yy * W_ + xx];
                                }
                            }
                    }
                }
                ushort_t hi, lo; split_bf16(sv, hi, lo);
                Bs[0][p][c] = hi;
                Bs[1][p][c] = lo;
            }
            __syncthreads();

            // ---- fragments + MFMA ----
            short8 ah[2], al[2];
#pragma unroll
            for (int mt = 0; mt < 2; ++mt) {
                const ushort_t* arow = w2p +
                    ((size_t)(k * 256 + (mW + mt * 16 + l15)) * 2) * 256 +
                    cb + quad * 8;
                ah[mt] = *(const short8*)(arow);
                al[mt] = *(const short8*)(arow + 256);
            }
            short8 bh[4], bl[4];
#pragma unroll
            for (int nt = 0; nt < 4; ++nt) {
                bh[nt] = ld_frag_lds(&Bs[0][nt * 16 + l15][quad * 8]);
                bl[nt] = ld_frag_lds(&Bs[1][nt * 16 + l15][quad * 8]);
            }
#pragma unroll
            for (int mt = 0; mt < 2; ++mt)
#pragma unroll
                for (int nt = 0; nt < 4; ++nt) {
                    acc[mt][nt] = __builtin_amdgcn_mfma_f32_16x16x32_bf16(
                        ah[mt], bh[nt], acc[mt][nt], 0, 0, 0);
                    acc[mt][nt] = __builtin_amdgcn_mfma_f32_16x16x32_bf16(
                        ah[mt], bl[nt], acc[mt][nt], 0, 0, 0);
                    acc[mt][nt] = __builtin_amdgcn_mfma_f32_16x16x32_bf16(
                        al[mt], bh[nt], acc[mt][nt], 0, 0, 0);
                }
        }
    }

    // ---- epilogue: bias + relu ----
#pragma unroll
    for (int mt = 0; mt < 2; ++mt)
#pragma unroll
        for (int rr = 0; rr < 4; ++rr) {
            int o = mW + mt * 16 + quad * 4 + rr;
            float bv = b2[o];
#pragma unroll
            for (int nt = 0; nt < 4; ++nt) {
                int p = nt * 16 + l15;
                if (p < 56) {
                    float v = fmaxf(acc[mt][nt][rr] + bv, 0.f);
                    r2[((size_t)n * CB + o) * HW + h * W_ + p] = v;
                }
            }
        }
}

// ---------------------------------------------------------------------------
// kernel_launch
// ---------------------------------------------------------------------------
extern "C" void kernel_launch(void* const* d_in, const int* in_sizes, int n_in,
                              void* d_out, int out_size, void* d_ws, size_t ws_size,
                              hipStream_t stream)
{
    const float* x     = (const float*)d_in[0];
    const float* w1    = (const float*)d_in[1];
    const float* b1    = (const float*)d_in[2];
    const float* w_off = (const float*)d_in[3];
    const float* b_off = (const float*)d_in[4];
    const float* w2    = (const float*)d_in[5];
    const float* b2    = (const float*)d_in[6];
    const float* w3    = (const float*)d_in[7];
    const float* b3    = (const float*)d_in[8];
    float* out = (float*)d_out;

    float* ws  = (float*)d_ws;
    float* r    = ws;                             // 3,211,264 f
    float* r2   = r  + (size_t)N_ * CB * HW;      // 3,211,264 f
    float* offb = r2 + (size_t)N_ * CB * HW;      //   225,792 f
    ushort_t* w1p = (ushort_t*)(offb + (size_t)N_ * OFFC * HW); // 524,288 us
    ushort_t* w2p = w1p + (size_t)256 * 2 * 1024;               // 1,179,648 us
    ushort_t* w3p = w2p + (size_t)9 * 256 * 2 * 256;            //   524,288 us

    // 1) pack weights (hi/lo bf16 planes)
    {
        int total = 256 * 1024 + 256 * 256 * 9 + 1024 * 256;   // 1,114,112
        pack_weights_kernel<<<(total + 255) / 256, 256, 0, stream>>>(
            w1, w2, w3, w1p, w2p, w3p);
    }
    // 2) r = relu(w1 . x + b1)    M=256, K=1024
    {
        dim3 grid(HW / 64, 1, N_);
        conv1x1_mfma_kernel<true, false><<<grid, 256, 0, stream>>>(
            w1p, x, b1, nullptr, r, CB, CIN);
    }
    // 3) off = conv3x3(r, w_off) + b_off
    {
        int total = N_ * OFFC * HW;
        offset_conv_kernel<<<(total + 255) / 256, 256, 0, stream>>>(
            r, w_off, b_off, offb);
    }
    // 4) r2 = relu(deform(r, off) . w2 + b2)
    {
        dim3 grid(H_, 2, N_);
        deform_mfma_kernel<<<grid, 256, 0, stream>>>(r, offb, w2p, b2, r2);
    }
    // 5) out = relu(x + w3 . r2 + b3)   M=1024, K=256
    {
        dim3 grid(HW / 64, 4, N_);
        conv1x1_mfma_kernel<true, true><<<grid, 256, 0, stream>>>(
            w3p, r2, b3, x, out, CIN, CB);
    }
}

// Round 3
// 506.935 us; speedup vs baseline: 2.3976x; 1.5116x over previous
//
#include <hip/hip_runtime.h>
#include <hip/hip_bf16.h>

#define N_   4
#define CIN  1024
#define H_   56
#define W_   56
#define HW   3136
#define CB   256
#define KK   9
#define OFFC 18

typedef __attribute__((ext_vector_type(8))) short short8;
typedef __attribute__((ext_vector_type(4))) short short4v;
typedef __attribute__((ext_vector_type(4))) float float4v;
typedef unsigned short ushort_t;

// fp32 -> bf16 round-to-nearest-even
__device__ inline ushort_t bf16_rne(float f) {
    unsigned int u = __float_as_uint(f);
    unsigned int r = (u + 0x7FFFu + ((u >> 16) & 1u)) >> 16;
    return (ushort_t)r;
}
__device__ inline void split_bf16(float f, ushort_t& hi, ushort_t& lo) {
    ushort_t h = bf16_rne(f);
    float hf = __uint_as_float(((unsigned int)h) << 16);
    hi = h;
    lo = bf16_rne(f - hf);
}
__device__ inline short8 ld_frag_lds(const ushort_t* base) {
    short4v a = *(const short4v*)base;
    short4v b = *(const short4v*)(base + 4);
    return __builtin_shufflevector(a, b, 0, 1, 2, 3, 4, 5, 6, 7);
}

// ---------------------------------------------------------------------------
// Pack weights into split bf16 hi/lo planes (+ w_off single-plane bf16).
// w1 [256][1024]      -> w1p [o][2][1024]
// w2 [256][256][9]    -> w2p [k][o][2][256]
// w3 [1024][256]      -> w3p [o][2][256]
// w_off [18][256][9]  -> wofp [k][32][256]   (m padded 18->32 with zeros)
// ---------------------------------------------------------------------------
__global__ void __launch_bounds__(256) pack_weights_kernel(
    const float* __restrict__ w1, const float* __restrict__ w2,
    const float* __restrict__ w3, const float* __restrict__ w_off,
    ushort_t* __restrict__ w1p, ushort_t* __restrict__ w2p,
    ushort_t* __restrict__ w3p, ushort_t* __restrict__ wofp)
{
    int e = blockIdx.x * 256 + threadIdx.x;
    if (e < 256 * 1024) {
        int o = e >> 10, k = e & 1023;
        ushort_t hi, lo; split_bf16(w1[e], hi, lo);
        w1p[(size_t)(o * 2 + 0) * 1024 + k] = hi;
        w1p[(size_t)(o * 2 + 1) * 1024 + k] = lo;
        return;
    }
    e -= 256 * 1024;
    if (e < 256 * 256 * 9) {
        int o = e / 2304; int rem = e % 2304; int c = rem / 9; int k = rem % 9;
        ushort_t hi, lo; split_bf16(w2[e], hi, lo);
        size_t base = ((size_t)(k * 256 + o) * 2) * 256 + c;
        w2p[base] = hi; w2p[base + 256] = lo;
        return;
    }
    e -= 256 * 256 * 9;
    if (e < 1024 * 256) {
        int o = e >> 8, k = e & 255;
        ushort_t hi, lo; split_bf16(w3[e], hi, lo);
        w3p[(size_t)(o * 2 + 0) * 256 + k] = hi;
        w3p[(size_t)(o * 2 + 1) * 256 + k] = lo;
        return;
    }
    e -= 1024 * 256;
    if (e < 9 * 32 * 256) {
        int k = e / (32 * 256);
        int rem = e % (32 * 256);
        int m = rem >> 8, c = rem & 255;
        float v = (m < OFFC) ? w_off[((size_t)m * 256 + c) * 9 + k] : 0.f;
        wofp[e] = bf16_rne(v);
    }
}

// ---------------------------------------------------------------------------
// 1x1 conv via MFMA, split-bf16 3-pass.
// ---------------------------------------------------------------------------
template <bool RELU, bool RESID>
__global__ void __launch_bounds__(256, 2) conv1x1_mfma_kernel(
    const ushort_t* __restrict__ Wp,   // [M][2][Kdim]
    const float* __restrict__ Xin,     // [n][Kdim][HW]
    const float* __restrict__ bias,    // [M]
    const float* __restrict__ resid,   // [n][M][HW] or null
    float* __restrict__ Cout,          // [n][M][HW]
    int M, int Kdim)
{
    __shared__ ushort_t Bs[2][64][36];   // [plane][p][k], pad 36

    const int tid  = threadIdx.x;
    const int wave = tid >> 6;
    const int lane = tid & 63;
    const int l15  = lane & 15;
    const int quad = lane >> 4;
    const int pBase = blockIdx.x * 64;
    const int mBase = blockIdx.y * 256 + wave * 64;
    const int n     = blockIdx.z;
    const float* Xn = Xin + (size_t)n * Kdim * HW;

    float4v acc[4][4];
#pragma unroll
    for (int i = 0; i < 4; ++i)
#pragma unroll
        for (int j = 0; j < 4; ++j) acc[i][j] = (float4v)(0.f);

    const int kk = tid >> 3;          // 0..31
    const int pq = (tid & 7) * 8;     // 0..56

    for (int k0 = 0; k0 < Kdim; k0 += 32) {
        const float* src = &Xn[(size_t)(k0 + kk) * HW + pBase + pq];
        float4 v0 = *reinterpret_cast<const float4*>(src);
        float4 v1 = *reinterpret_cast<const float4*>(src + 4);
        __syncthreads();   // previous iter's Bs reads are done
        float vs[8] = {v0.x, v0.y, v0.z, v0.w, v1.x, v1.y, v1.z, v1.w};
#pragma unroll
        for (int j = 0; j < 8; ++j) {
            ushort_t hi, lo; split_bf16(vs[j], hi, lo);
            Bs[0][pq + j][kk] = hi;
            Bs[1][pq + j][kk] = lo;
        }
        __syncthreads();

        short8 ah[4], al[4];
#pragma unroll
        for (int mt = 0; mt < 4; ++mt) {
            const ushort_t* arow = Wp +
                ((size_t)(mBase + mt * 16 + l15) * 2) * Kdim + k0 + quad * 8;
            ah[mt] = *(const short8*)(arow);
            al[mt] = *(const short8*)(arow + Kdim);
        }
        short8 bh[4], bl[4];
#pragma unroll
        for (int nt = 0; nt < 4; ++nt) {
            bh[nt] = ld_frag_lds(&Bs[0][nt * 16 + l15][quad * 8]);
            bl[nt] = ld_frag_lds(&Bs[1][nt * 16 + l15][quad * 8]);
        }
#pragma unroll
        for (int mt = 0; mt < 4; ++mt)
#pragma unroll
            for (int nt = 0; nt < 4; ++nt) {
                acc[mt][nt] = __builtin_amdgcn_mfma_f32_16x16x32_bf16(
                    ah[mt], bh[nt], acc[mt][nt], 0, 0, 0);
                acc[mt][nt] = __builtin_amdgcn_mfma_f32_16x16x32_bf16(
                    ah[mt], bl[nt], acc[mt][nt], 0, 0, 0);
                acc[mt][nt] = __builtin_amdgcn_mfma_f32_16x16x32_bf16(
                    al[mt], bh[nt], acc[mt][nt], 0, 0, 0);
            }
    }

#pragma unroll
    for (int mt = 0; mt < 4; ++mt)
#pragma unroll
        for (int rr = 0; rr < 4; ++rr) {
            int row = mBase + mt * 16 + quad * 4 + rr;
            float bv = bias[row];
#pragma unroll
            for (int nt = 0; nt < 4; ++nt) {
                int col = pBase + nt * 16 + l15;
                size_t idx = ((size_t)n * M + row) * HW + col;
                float v = acc[mt][nt][rr] + bv;
                if (RESID) v += resid[idx];
                if (RELU)  v = fmaxf(v, 0.f);
                Cout[idx] = v;
            }
        }
}

// ---------------------------------------------------------------------------
// Offset conv 3x3 via MFMA (bf16 1-pass), LDS row-window staging.
// One block per (row h, n). 256 thr = 4 waves; wave w owns positions
// [w*16, w*16+16). M=32 (18 real), K=2304 in 8 chunks of 32 ch x 9 taps.
// win c-stride 174: quad offset 8*174=1392 -> 16 banks -> 2-way (free).
// ---------------------------------------------------------------------------
__global__ void __launch_bounds__(256, 2) offset_mfma_kernel(
    const float* __restrict__ r,        // [n][CB][HW]
    const ushort_t* __restrict__ wofp,  // [9][32][256] bf16
    const float* __restrict__ b_off,    // [18]
    float* __restrict__ off)            // [n][18][HW]
{
    __shared__ float win[32][174];      // 3 rows x 56 cols, padded stride

    const int tid  = threadIdx.x;
    const int h    = blockIdx.x;
    const int n    = blockIdx.y;
    const int wave = tid >> 6;
    const int lane = tid & 63;
    const int l15  = lane & 15;
    const int quad = lane >> 4;
    const float* rn = r + (size_t)n * CB * HW;

    const int p = wave * 16 + l15;      // output column this lane covers

    float4v acc[2];
    acc[0] = (float4v)(0.f);
    acc[1] = (float4v)(0.f);

    for (int cb = 0; cb < CB; cb += 32) {
        __syncthreads();
        // stage 32 ch x 3 rows (h-1..h+1, zero at borders) x 56 cols
        for (int f = tid; f < 32 * 3 * 14; f += 256) {
            int c = f / 42, remf = f % 42, row = remf / 14, x4 = (remf % 14) * 4;
            int yg = h - 1 + row;
            float4 v = {0.f, 0.f, 0.f, 0.f};
            if (yg >= 0 && yg < H_)
                v = *reinterpret_cast<const float4*>(
                    &rn[(size_t)(cb + c) * HW + yg * W_ + x4]);
            *reinterpret_cast<float4*>(&win[c][row * 56 + x4]) = v;
        }
        __syncthreads();

#pragma unroll
        for (int k = 0; k < KK; ++k) {
            const int ky = k / 3;
            const int dx = (k % 3) - 1;
            int x = p + dx;
            bool pvalid = (p < 56) && (x >= 0) && (x < 56);
            int xc = min(max(x, 0), 55);
            short8 bh;
#pragma unroll
            for (int j = 0; j < 8; ++j) {
                float v = win[quad * 8 + j][ky * 56 + xc];
                bh[j] = (short)bf16_rne(pvalid ? v : 0.f);
            }
#pragma unroll
            for (int mt = 0; mt < 2; ++mt) {
                const ushort_t* arow = wofp +
                    (size_t)(k * 32 + mt * 16 + l15) * 256 + cb + quad * 8;
                short8 ah = *(const short8*)arow;
                acc[mt] = __builtin_amdgcn_mfma_f32_16x16x32_bf16(
                    ah, bh, acc[mt], 0, 0, 0);
            }
        }
    }

    if (p < 56) {
#pragma unroll
        for (int mt = 0; mt < 2; ++mt)
#pragma unroll
            for (int rr = 0; rr < 4; ++rr) {
                int m = mt * 16 + quad * 4 + rr;
                if (m < OFFC)
                    off[((size_t)n * OFFC + m) * HW + h * W_ + p] =
                        acc[mt][rr] + b_off[m];
            }
    }
}

// ---------------------------------------------------------------------------
// Deformable conv via MFMA, split-bf16 3-pass, LDS window staging.
// ---------------------------------------------------------------------------
__global__ void __launch_bounds__(256, 2) deform_mfma_kernel(
    const float* __restrict__ r,      // [n][CB][HW]
    const float* __restrict__ off,    // [n][18][HW]
    const ushort_t* __restrict__ w2p, // [9][256][2][256]
    const float* __restrict__ b2,
    float* __restrict__ r2)           // [n][CB][HW]
{
    __shared__ float    win[32][280];        // 5 rows x 56 cols per channel
    __shared__ ushort_t Bs[2][64][36];
    __shared__ short    widx[KK][56][4];
    __shared__ float    wwgt[KK][56][4];
    __shared__ unsigned char fastf[KK][56];

    const int tid   = threadIdx.x;
    const int h     = blockIdx.x;           // 0..55
    const int oBase = blockIdx.y * 128;
    const int n     = blockIdx.z;
    const float* rn   = r + (size_t)n * CB * HW;
    const float* offn = off + (size_t)n * OFFC * HW;

    // ---- per-(tap, position) bilinear metadata, window-relative ----
    for (int e = tid; e < KK * 56; e += 256) {
        int k = e / 56, p = e % 56;
        float dy = offn[(size_t)(2 * k) * HW + h * W_ + p];
        float dx = offn[(size_t)(2 * k + 1) * HW + h * W_ + p];
        float ys = (float)(h + (k / 3) - 1) + dy;
        float xs = (float)(p + (k % 3) - 1) + dx;
        float y0f = floorf(ys), x0f = floorf(xs);
        int y0 = (int)y0f, x0 = (int)x0f;
        float wy1 = ys - y0f, wy0 = 1.f - wy1;
        float wx1 = xs - x0f, wx0 = 1.f - wx1;
        bool fast = true;
#pragma unroll
        for (int u = 0; u < 2; ++u)
#pragma unroll
            for (int vv = 0; vv < 2; ++vv) {
                int yy = y0 + u, xx = x0 + vv;
                bool valid = (yy >= 0) && (yy <= 55) && (xx >= 0) && (xx <= 55);
                float wgt = valid ? (u ? wy1 : wy0) * (vv ? wx1 : wx0) : 0.f;
                int slot = yy - (h - 2);
                if (wgt != 0.f && (slot < 0 || slot > 4)) fast = false;
                int slotc = min(max(slot, 0), 4);
                int xc = min(max(xx, 0), 55);
                widx[k][p][u * 2 + vv] = (short)(slotc * 56 + xc);
                wwgt[k][p][u * 2 + vv] = wgt;
            }
        fastf[k][p] = fast ? 1 : 0;
    }

    const int wave = tid >> 6;
    const int lane = tid & 63;
    const int l15  = lane & 15;
    const int quad = lane >> 4;
    const int mW   = oBase + wave * 32;

    float4v acc[2][4];
#pragma unroll
    for (int i = 0; i < 2; ++i)
#pragma unroll
        for (int j = 0; j < 4; ++j) acc[i][j] = (float4v)(0.f);

    for (int cb = 0; cb < CB; cb += 32) {
        __syncthreads();  // prev Bs/win reads done; meta ready on first iter
        // ---- stage window: 32 ch x 5 rows x 56 cols ----
        for (int f = tid; f < 2240; f += 256) {
            int c = f / 70;
            int remf = f % 70;
            int row = remf / 14;
            int x4 = (remf % 14) * 4;
            int rowg = min(max(h - 2 + row, 0), 55);
            const float4* src = reinterpret_cast<const float4*>(
                &rn[(size_t)(cb + c) * HW + rowg * W_ + x4]);
            *reinterpret_cast<float4*>(&win[c][row * 56 + x4]) = *src;
        }
        __syncthreads();

        for (int k = 0; k < KK; ++k) {
            if (k) __syncthreads();  // prev tap's Bs reads done
            // ---- build B tile: samples for 32 ch x 64 p ----
#pragma unroll
            for (int ii = 0; ii < 8; ++ii) {
                int e = tid + 256 * ii;
                int c = e >> 6, p = e & 63;
                float sv = 0.f;
                if (p < 56) {
                    if (fastf[k][p]) {
                        const float* wc = win[c];
                        short4v id4 = *(const short4v*)&widx[k][p][0];
                        float4 w4 = *reinterpret_cast<const float4*>(&wwgt[k][p][0]);
                        sv = w4.x * wc[id4.x] + w4.y * wc[id4.y] +
                             w4.z * wc[id4.z] + w4.w * wc[id4.w];
                    } else {
                        float dy = offn[(size_t)(2 * k) * HW + h * W_ + p];
                        float dx = offn[(size_t)(2 * k + 1) * HW + h * W_ + p];
                        float ys = (float)(h + (k / 3) - 1) + dy;
                        float xs = (float)(p + (k % 3) - 1) + dx;
                        float y0f = floorf(ys), x0f = floorf(xs);
                        int y0 = (int)y0f, x0 = (int)x0f;
                        float wy1 = ys - y0f, wy0 = 1.f - wy1;
                        float wx1 = xs - x0f, wx0 = 1.f - wx1;
                        const float* rc = rn + (size_t)(cb + c) * HW;
#pragma unroll
                        for (int u = 0; u < 2; ++u)
#pragma unroll
                            for (int vv = 0; vv < 2; ++vv) {
                                int yy = y0 + u, xx = x0 + vv;
                                if (yy >= 0 && yy <= 55 && xx >= 0 && xx <= 55) {
                                    float wgt = (u ? wy1 : wy0) * (vv ? wx1 : wx0);
                                    sv += wgt * rc[yy * W_ + xx];
                                }
                            }
                    }
                }
                ushort_t hi, lo; split_bf16(sv, hi, lo);
                Bs[0][p][c] = hi;
                Bs[1][p][c] = lo;
            }
            __syncthreads();

            // ---- fragments + MFMA ----
            short8 ah[2], al[2];
#pragma unroll
            for (int mt = 0; mt < 2; ++mt) {
                const ushort_t* arow = w2p +
                    ((size_t)(k * 256 + (mW + mt * 16 + l15)) * 2) * 256 +
                    cb + quad * 8;
                ah[mt] = *(const short8*)(arow);
                al[mt] = *(const short8*)(arow + 256);
            }
            short8 bh[4], bl[4];
#pragma unroll
            for (int nt = 0; nt < 4; ++nt) {
                bh[nt] = ld_frag_lds(&Bs[0][nt * 16 + l15][quad * 8]);
                bl[nt] = ld_frag_lds(&Bs[1][nt * 16 + l15][quad * 8]);
            }
#pragma unroll
            for (int mt = 0; mt < 2; ++mt)
#pragma unroll
                for (int nt = 0; nt < 4; ++nt) {
                    acc[mt][nt] = __builtin_amdgcn_mfma_f32_16x16x32_bf16(
                        ah[mt], bh[nt], acc[mt][nt], 0, 0, 0);
                    acc[mt][nt] = __builtin_amdgcn_mfma_f32_16x16x32_bf16(
                        ah[mt], bl[nt], acc[mt][nt], 0, 0, 0);
                    acc[mt][nt] = __builtin_amdgcn_mfma_f32_16x16x32_bf16(
                        al[mt], bh[nt], acc[mt][nt], 0, 0, 0);
                }
        }
    }

    // ---- epilogue: bias + relu ----
#pragma unroll
    for (int mt = 0; mt < 2; ++mt)
#pragma unroll
        for (int rr = 0; rr < 4; ++rr) {
            int o = mW + mt * 16 + quad * 4 + rr;
            float bv = b2[o];
#pragma unroll
            for (int nt = 0; nt < 4; ++nt) {
                int p = nt * 16 + l15;
                if (p < 56) {
                    float v = fmaxf(acc[mt][nt][rr] + bv, 0.f);
                    r2[((size_t)n * CB + o) * HW + h * W_ + p] = v;
                }
            }
        }
}

// ---------------------------------------------------------------------------
// kernel_launch
// ---------------------------------------------------------------------------
extern "C" void kernel_launch(void* const* d_in, const int* in_sizes, int n_in,
                              void* d_out, int out_size, void* d_ws, size_t ws_size,
                              hipStream_t stream)
{
    const float* x     = (const float*)d_in[0];
    const float* w1    = (const float*)d_in[1];
    const float* b1    = (const float*)d_in[2];
    const float* w_off = (const float*)d_in[3];
    const float* b_off = (const float*)d_in[4];
    const float* w2    = (const float*)d_in[5];
    const float* b2    = (const float*)d_in[6];
    const float* w3    = (const float*)d_in[7];
    const float* b3    = (const float*)d_in[8];
    float* out = (float*)d_out;

    float* ws  = (float*)d_ws;
    float* r    = ws;                             // 3,211,264 f
    float* r2   = r  + (size_t)N_ * CB * HW;      // 3,211,264 f
    float* offb = r2 + (size_t)N_ * CB * HW;      //   225,792 f
    ushort_t* w1p  = (ushort_t*)(offb + (size_t)N_ * OFFC * HW); // 524,288 us
    ushort_t* w2p  = w1p + (size_t)256 * 2 * 1024;               // 1,179,648 us
    ushort_t* w3p  = w2p + (size_t)9 * 256 * 2 * 256;            //   524,288 us
    ushort_t* wofp = w3p + (size_t)1024 * 2 * 256;               //    73,728 us

    // 1) pack weights (hi/lo bf16 planes; w_off single plane)
    {
        int total = 256 * 1024 + 256 * 256 * 9 + 1024 * 256 + 9 * 32 * 256;
        pack_weights_kernel<<<(total + 255) / 256, 256, 0, stream>>>(
            w1, w2, w3, w_off, w1p, w2p, w3p, wofp);
    }
    // 2) r = relu(w1 . x + b1)    M=256, K=1024
    {
        dim3 grid(HW / 64, 1, N_);
        conv1x1_mfma_kernel<true, false><<<grid, 256, 0, stream>>>(
            w1p, x, b1, nullptr, r, CB, CIN);
    }
    // 3) off = conv3x3(r, w_off) + b_off   (MFMA, bf16 1-pass)
    {
        dim3 grid(H_, N_);
        offset_mfma_kernel<<<grid, 256, 0, stream>>>(r, wofp, b_off, offb);
    }
    // 4) r2 = relu(deform(r, off) . w2 + b2)
    {
        dim3 grid(H_, 2, N_);
        deform_mfma_kernel<<<grid, 256, 0, stream>>>(r, offb, w2p, b2, r2);
    }
    // 5) out = relu(x + w3 . r2 + b3)   M=1024, K=256
    {
        dim3 grid(HW / 64, 4, N_);
        conv1x1_mfma_kernel<true, true><<<grid, 256, 0, stream>>>(
            w3p, r2, b3, x, out, CIN, CB);
    }
}

// Round 4
// 410.784 us; speedup vs baseline: 2.9588x; 1.2341x over previous
//
#include <hip/hip_runtime.h>
#include <hip/hip_bf16.h>

#define N_   4
#define CIN  1024
#define H_   56
#define W_   56
#define HW   3136
#define CB   256
#define KK   9
#define OFFC 18

typedef __attribute__((ext_vector_type(8))) short short8;
typedef __attribute__((ext_vector_type(4))) short short4v;
typedef __attribute__((ext_vector_type(4))) float float4v;
typedef unsigned short ushort_t;

// fp32 -> bf16 round-to-nearest-even
__device__ inline ushort_t bf16_rne(float f) {
    unsigned int u = __float_as_uint(f);
    unsigned int r = (u + 0x7FFFu + ((u >> 16) & 1u)) >> 16;
    return (ushort_t)r;
}
__device__ inline void split_bf16(float f, ushort_t& hi, ushort_t& lo) {
    ushort_t h = bf16_rne(f);
    float hf = __uint_as_float(((unsigned int)h) << 16);
    hi = h;
    lo = bf16_rne(f - hf);
}
__device__ inline short8 ld_frag_lds(const ushort_t* base) {
    short4v a = *(const short4v*)base;
    short4v b = *(const short4v*)(base + 4);
    return __builtin_shufflevector(a, b, 0, 1, 2, 3, 4, 5, 6, 7);
}

// ---------------------------------------------------------------------------
// Pack weights into split bf16 hi/lo planes (+ w_off single-plane bf16).
// w1 [256][1024]      -> w1p [o][2][1024]
// w2 [256][256][9]    -> w2p [k][o][2][256]
// w3 [1024][256]      -> w3p [o][2][256]
// w_off [18][256][9]  -> wofp [k][32][256]   (m padded 18->32 with zeros)
// ---------------------------------------------------------------------------
__global__ void __launch_bounds__(256) pack_weights_kernel(
    const float* __restrict__ w1, const float* __restrict__ w2,
    const float* __restrict__ w3, const float* __restrict__ w_off,
    ushort_t* __restrict__ w1p, ushort_t* __restrict__ w2p,
    ushort_t* __restrict__ w3p, ushort_t* __restrict__ wofp)
{
    int e = blockIdx.x * 256 + threadIdx.x;
    if (e < 256 * 1024) {
        int o = e >> 10, k = e & 1023;
        ushort_t hi, lo; split_bf16(w1[e], hi, lo);
        w1p[(size_t)(o * 2 + 0) * 1024 + k] = hi;
        w1p[(size_t)(o * 2 + 1) * 1024 + k] = lo;
        return;
    }
    e -= 256 * 1024;
    if (e < 256 * 256 * 9) {
        int o = e / 2304; int rem = e % 2304; int c = rem / 9; int k = rem % 9;
        ushort_t hi, lo; split_bf16(w2[e], hi, lo);
        size_t base = ((size_t)(k * 256 + o) * 2) * 256 + c;
        w2p[base] = hi; w2p[base + 256] = lo;
        return;
    }
    e -= 256 * 256 * 9;
    if (e < 1024 * 256) {
        int o = e >> 8, k = e & 255;
        ushort_t hi, lo; split_bf16(w3[e], hi, lo);
        w3p[(size_t)(o * 2 + 0) * 256 + k] = hi;
        w3p[(size_t)(o * 2 + 1) * 256 + k] = lo;
        return;
    }
    e -= 1024 * 256;
    if (e < 9 * 32 * 256) {
        int k = e / (32 * 256);
        int rem = e % (32 * 256);
        int m = rem >> 8, c = rem & 255;
        float v = (m < OFFC) ? w_off[((size_t)m * 256 + c) * 9 + k] : 0.f;
        wofp[e] = bf16_rne(v);
    }
}

// ---------------------------------------------------------------------------
// 1x1 conv via MFMA. A = weights (hi/lo split, 2 passes), B = activations
// (single bf16 plane). Block 256 thr = 4 waves; per wave M = MFRAG*16;
// block M = MFRAG*64. BN=64, BK=32.
// ---------------------------------------------------------------------------
template <int MFRAG, bool RELU, bool RESID>
__global__ void __launch_bounds__(256, 4) conv1x1_mfma_kernel(
    const ushort_t* __restrict__ Wp,   // [M][2][Kdim]
    const float* __restrict__ Xin,     // [n][Kdim][HW]
    const float* __restrict__ bias,    // [M]
    const float* __restrict__ resid,   // [n][M][HW] or null
    float* __restrict__ Cout,          // [n][M][HW]
    int M, int Kdim)
{
    __shared__ ushort_t Bs[64][36];   // [p][k], pad 36

    const int tid  = threadIdx.x;
    const int wave = tid >> 6;
    const int lane = tid & 63;
    const int l15  = lane & 15;
    const int quad = lane >> 4;
    const int pBase = blockIdx.x * 64;
    const int mBase = blockIdx.y * (MFRAG * 64) + wave * (MFRAG * 16);
    const int n     = blockIdx.z;
    const float* Xn = Xin + (size_t)n * Kdim * HW;

    float4v acc[MFRAG][4];
#pragma unroll
    for (int i = 0; i < MFRAG; ++i)
#pragma unroll
        for (int j = 0; j < 4; ++j) acc[i][j] = (float4v)(0.f);

    const int kk = tid >> 3;          // 0..31
    const int pq = (tid & 7) * 8;     // 0..56

    for (int k0 = 0; k0 < Kdim; k0 += 32) {
        const float* src = &Xn[(size_t)(k0 + kk) * HW + pBase + pq];
        float4 v0 = *reinterpret_cast<const float4*>(src);
        float4 v1 = *reinterpret_cast<const float4*>(src + 4);
        __syncthreads();   // previous iter's Bs reads are done
        float vs[8] = {v0.x, v0.y, v0.z, v0.w, v1.x, v1.y, v1.z, v1.w};
#pragma unroll
        for (int j = 0; j < 8; ++j) Bs[pq + j][kk] = bf16_rne(vs[j]);
        __syncthreads();

        short8 ah[MFRAG], al[MFRAG];
#pragma unroll
        for (int mt = 0; mt < MFRAG; ++mt) {
            const ushort_t* arow = Wp +
                ((size_t)(mBase + mt * 16 + l15) * 2) * Kdim + k0 + quad * 8;
            ah[mt] = *(const short8*)(arow);
            al[mt] = *(const short8*)(arow + Kdim);
        }
        short8 bh[4];
#pragma unroll
        for (int nt = 0; nt < 4; ++nt)
            bh[nt] = ld_frag_lds(&Bs[nt * 16 + l15][quad * 8]);
#pragma unroll
        for (int mt = 0; mt < MFRAG; ++mt)
#pragma unroll
            for (int nt = 0; nt < 4; ++nt) {
                acc[mt][nt] = __builtin_amdgcn_mfma_f32_16x16x32_bf16(
                    ah[mt], bh[nt], acc[mt][nt], 0, 0, 0);
                acc[mt][nt] = __builtin_amdgcn_mfma_f32_16x16x32_bf16(
                    al[mt], bh[nt], acc[mt][nt], 0, 0, 0);
            }
    }

#pragma unroll
    for (int mt = 0; mt < MFRAG; ++mt)
#pragma unroll
        for (int rr = 0; rr < 4; ++rr) {
            int row = mBase + mt * 16 + quad * 4 + rr;
            float bv = bias[row];
#pragma unroll
            for (int nt = 0; nt < 4; ++nt) {
                int col = pBase + nt * 16 + l15;
                size_t idx = ((size_t)n * M + row) * HW + col;
                float v = acc[mt][nt][rr] + bv;
                if (RESID) v += resid[idx];
                if (RELU)  v = fmaxf(v, 0.f);
                Cout[idx] = v;
            }
        }
}

// ---------------------------------------------------------------------------
// Offset conv 3x3 via MFMA (bf16 1-pass), LDS row-window staging.
// ---------------------------------------------------------------------------
__global__ void __launch_bounds__(256, 2) offset_mfma_kernel(
    const float* __restrict__ r,        // [n][CB][HW]
    const ushort_t* __restrict__ wofp,  // [9][32][256] bf16
    const float* __restrict__ b_off,    // [18]
    float* __restrict__ off)            // [n][18][HW]
{
    __shared__ float win[32][174];      // 3 rows x 56 cols, padded stride

    const int tid  = threadIdx.x;
    const int h    = blockIdx.x;
    const int n    = blockIdx.y;
    const int wave = tid >> 6;
    const int lane = tid & 63;
    const int l15  = lane & 15;
    const int quad = lane >> 4;
    const float* rn = r + (size_t)n * CB * HW;

    const int p = wave * 16 + l15;      // output column this lane covers

    float4v acc[2];
    acc[0] = (float4v)(0.f);
    acc[1] = (float4v)(0.f);

    for (int cb = 0; cb < CB; cb += 32) {
        __syncthreads();
        for (int f = tid; f < 32 * 3 * 14; f += 256) {
            int c = f / 42, remf = f % 42, row = remf / 14, x4 = (remf % 14) * 4;
            int yg = h - 1 + row;
            float4 v = {0.f, 0.f, 0.f, 0.f};
            if (yg >= 0 && yg < H_)
                v = *reinterpret_cast<const float4*>(
                    &rn[(size_t)(cb + c) * HW + yg * W_ + x4]);
            *reinterpret_cast<float4*>(&win[c][row * 56 + x4]) = v;
        }
        __syncthreads();

#pragma unroll
        for (int k = 0; k < KK; ++k) {
            const int ky = k / 3;
            const int dx = (k % 3) - 1;
            int x = p + dx;
            bool pvalid = (p < 56) && (x >= 0) && (x < 56);
            int xc = min(max(x, 0), 55);
            short8 bh;
#pragma unroll
            for (int j = 0; j < 8; ++j) {
                float v = win[quad * 8 + j][ky * 56 + xc];
                bh[j] = (short)bf16_rne(pvalid ? v : 0.f);
            }
#pragma unroll
            for (int mt = 0; mt < 2; ++mt) {
                const ushort_t* arow = wofp +
                    (size_t)(k * 32 + mt * 16 + l15) * 256 + cb + quad * 8;
                short8 ah = *(const short8*)arow;
                acc[mt] = __builtin_amdgcn_mfma_f32_16x16x32_bf16(
                    ah, bh, acc[mt], 0, 0, 0);
            }
        }
    }

    if (p < 56) {
#pragma unroll
        for (int mt = 0; mt < 2; ++mt)
#pragma unroll
            for (int rr = 0; rr < 4; ++rr) {
                int m = mt * 16 + quad * 4 + rr;
                if (m < OFFC)
                    off[((size_t)n * OFFC + m) * HW + h * W_ + p] =
                        acc[mt][rr] + b_off[m];
            }
    }
}

// ---------------------------------------------------------------------------
// Deformable conv via MFMA. 512 thr = 8 waves; block covers all 256 outputs
// (M=256, wave: 32 m) x 28 positions (x-half), N-tile 32. Window in LDS,
// layout win[pos][c] with odd c-stride 33 -> conflict-free random gather.
// B = samples, single bf16 plane; A = w2 hi/lo (2 MFMA passes).
// Grid: (56 h, 2 xhalf, 4 n).
// ---------------------------------------------------------------------------
#define TPX   28
#define WROWS 5
#define WCOLS 36
#define WPOS  (WROWS * WCOLS)   // 180
#define CSTR  33

__global__ void __launch_bounds__(512, 4) deform_mfma_kernel(
    const float* __restrict__ r,      // [n][CB][HW]
    const float* __restrict__ off,    // [n][18][HW]
    const ushort_t* __restrict__ w2p, // [9][256][2][256]
    const float* __restrict__ b2,
    float* __restrict__ r2)           // [n][CB][HW]
{
    __shared__ float    win[WPOS][CSTR];        // 23760 B
    __shared__ ushort_t Bs[32][36];             // 2304 B
    __shared__ short    widx[KK][TPX][4];       // 2016 B
    __shared__ float    wwgt[KK][TPX][4];       // 4032 B
    __shared__ unsigned char fastf[KK][TPX];    // 252 B

    const int tid = threadIdx.x;
    const int h   = blockIdx.x;
    const int xb  = blockIdx.y * TPX;
    const int n   = blockIdx.z;
    const float* rn   = r + (size_t)n * CB * HW;
    const float* offn = off + (size_t)n * OFFC * HW;

    // ---- per-(tap, position) bilinear metadata, window-relative ----
    for (int e = tid; e < KK * TPX; e += 512) {
        int k = e / TPX, p = e % TPX;
        int pg = xb + p;
        float dy = offn[(size_t)(2 * k) * HW + h * W_ + pg];
        float dx = offn[(size_t)(2 * k + 1) * HW + h * W_ + pg];
        float ys = (float)(h + (k / 3) - 1) + dy;
        float xs = (float)(pg + (k % 3) - 1) + dx;
        float y0f = floorf(ys), x0f = floorf(xs);
        int y0 = (int)y0f, x0 = (int)x0f;
        float wy1 = ys - y0f, wy0 = 1.f - wy1;
        float wx1 = xs - x0f, wx0 = 1.f - wx1;
        bool fast = true;
#pragma unroll
        for (int u = 0; u < 2; ++u)
#pragma unroll
            for (int vv = 0; vv < 2; ++vv) {
                int yy = y0 + u, xx = x0 + vv;
                bool valid = (yy >= 0) && (yy <= 55) && (xx >= 0) && (xx <= 55);
                float wgt = valid ? (u ? wy1 : wy0) * (vv ? wx1 : wx0) : 0.f;
                int ry = yy - (h - 2);
                int rx = xx - (xb - 4);
                if (wgt != 0.f &&
                    (ry < 0 || ry >= WROWS || rx < 0 || rx >= WCOLS))
                    fast = false;
                int ryc = min(max(ry, 0), WROWS - 1);
                int rxc = min(max(rx, 0), WCOLS - 1);
                widx[k][p][u * 2 + vv] = (short)(ryc * WCOLS + rxc);
                wwgt[k][p][u * 2 + vv] = wgt;
            }
        fastf[k][p] = fast ? 1 : 0;
    }

    const int wave = tid >> 6;     // 0..7
    const int lane = tid & 63;
    const int l15  = lane & 15;
    const int quad = lane >> 4;
    const int mW   = wave * 32;

    const int sc  = tid & 31;      // sampling: channel
    const int sp0 = tid >> 5;      // sampling: position base (0..15)

    float4v acc[2][2];
#pragma unroll
    for (int i = 0; i < 2; ++i)
#pragma unroll
        for (int j = 0; j < 2; ++j) acc[i][j] = (float4v)(0.f);

    for (int cb = 0; cb < CB; cb += 32) {
        __syncthreads();  // prior reads of win/Bs done; metadata visible
        // ---- stage window: 32 ch x 5 rows x 36 cols (x in [xb-4, xb+32)) ----
        for (int f = tid; f < 32 * WROWS * 9; f += 512) {
            int c = f / 45, remf = f % 45, row = remf / 9, q = remf % 9;
            int yg = min(max(h - 2 + row, 0), H_ - 1);
            int xg = xb - 4 + q * 4;
            const float* src = &rn[(size_t)(cb + c) * HW + yg * W_];
            float vx[4];
            if (xg >= 0 && xg <= W_ - 4) {
                float4 v = *reinterpret_cast<const float4*>(src + xg);
                vx[0] = v.x; vx[1] = v.y; vx[2] = v.z; vx[3] = v.w;
            } else {
#pragma unroll
                for (int j = 0; j < 4; ++j)
                    vx[j] = src[min(max(xg + j, 0), W_ - 1)];
            }
            int pos = row * WCOLS + q * 4;
#pragma unroll
            for (int j = 0; j < 4; ++j) win[pos + j][c] = vx[j];
        }
        __syncthreads();

        for (int k = 0; k < KK; ++k) {
            if (k) __syncthreads();  // prev tap's Bs frag reads done
            // ---- build B tile: 32 ch x 32 p (28 real) ----
#pragma unroll
            for (int ii = 0; ii < 2; ++ii) {
                int p = sp0 + 16 * ii;
                float sv = 0.f;
                if (p < TPX) {
                    if (fastf[k][p]) {
                        short4v id4 = *(const short4v*)&widx[k][p][0];
                        float4 w4 = *reinterpret_cast<const float4*>(&wwgt[k][p][0]);
                        sv = w4.x * win[id4.x][sc] + w4.y * win[id4.y][sc] +
                             w4.z * win[id4.z][sc] + w4.w * win[id4.w][sc];
                    } else {
                        int pg = xb + p;
                        float dy = offn[(size_t)(2 * k) * HW + h * W_ + pg];
                        float dx = offn[(size_t)(2 * k + 1) * HW + h * W_ + pg];
                        float ys = (float)(h + (k / 3) - 1) + dy;
                        float xs = (float)(pg + (k % 3) - 1) + dx;
                        float y0f = floorf(ys), x0f = floorf(xs);
                        int y0 = (int)y0f, x0 = (int)x0f;
                        float wy1 = ys - y0f, wy0 = 1.f - wy1;
                        float wx1 = xs - x0f, wx0 = 1.f - wx1;
                        const float* rc = rn + (size_t)(cb + sc) * HW;
#pragma unroll
                        for (int u = 0; u < 2; ++u)
#pragma unroll
                            for (int vv = 0; vv < 2; ++vv) {
                                int yy = y0 + u, xx = x0 + vv;
                                if (yy >= 0 && yy <= 55 && xx >= 0 && xx <= 55) {
                                    float wgt = (u ? wy1 : wy0) * (vv ? wx1 : wx0);
                                    sv += wgt * rc[yy * W_ + xx];
                                }
                            }
                    }
                }
                Bs[p][sc] = bf16_rne(sv);
            }
            __syncthreads();

            // ---- fragments + MFMA ----
            short8 ah[2], al[2];
#pragma unroll
            for (int mt = 0; mt < 2; ++mt) {
                const ushort_t* arow = w2p +
                    ((size_t)(k * 256 + (mW + mt * 16 + l15)) * 2) * 256 +
                    cb + quad * 8;
                ah[mt] = *(const short8*)(arow);
                al[mt] = *(const short8*)(arow + 256);
            }
            short8 bh[2];
#pragma unroll
            for (int nt = 0; nt < 2; ++nt)
                bh[nt] = ld_frag_lds(&Bs[nt * 16 + l15][quad * 8]);
#pragma unroll
            for (int mt = 0; mt < 2; ++mt)
#pragma unroll
                for (int nt = 0; nt < 2; ++nt) {
                    acc[mt][nt] = __builtin_amdgcn_mfma_f32_16x16x32_bf16(
                        ah[mt], bh[nt], acc[mt][nt], 0, 0, 0);
                    acc[mt][nt] = __builtin_amdgcn_mfma_f32_16x16x32_bf16(
                        al[mt], bh[nt], acc[mt][nt], 0, 0, 0);
                }
        }
    }

    // ---- epilogue: bias + relu ----
#pragma unroll
    for (int mt = 0; mt < 2; ++mt)
#pragma unroll
        for (int rr = 0; rr < 4; ++rr) {
            int o = mW + mt * 16 + quad * 4 + rr;
            float bv = b2[o];
#pragma unroll
            for (int nt = 0; nt < 2; ++nt) {
                int p = nt * 16 + l15;
                if (p < TPX) {
                    float v = fmaxf(acc[mt][nt][rr] + bv, 0.f);
                    r2[((size_t)n * CB + o) * HW + h * W_ + xb + p] = v;
                }
            }
        }
}

// ---------------------------------------------------------------------------
// kernel_launch
// ---------------------------------------------------------------------------
extern "C" void kernel_launch(void* const* d_in, const int* in_sizes, int n_in,
                              void* d_out, int out_size, void* d_ws, size_t ws_size,
                              hipStream_t stream)
{
    const float* x     = (const float*)d_in[0];
    const float* w1    = (const float*)d_in[1];
    const float* b1    = (const float*)d_in[2];
    const float* w_off = (const float*)d_in[3];
    const float* b_off = (const float*)d_in[4];
    const float* w2    = (const float*)d_in[5];
    const float* b2    = (const float*)d_in[6];
    const float* w3    = (const float*)d_in[7];
    const float* b3    = (const float*)d_in[8];
    float* out = (float*)d_out;

    float* ws  = (float*)d_ws;
    float* r    = ws;                             // 3,211,264 f
    float* r2   = r  + (size_t)N_ * CB * HW;      // 3,211,264 f
    float* offb = r2 + (size_t)N_ * CB * HW;      //   225,792 f
    ushort_t* w1p  = (ushort_t*)(offb + (size_t)N_ * OFFC * HW); // 524,288 us
    ushort_t* w2p  = w1p + (size_t)256 * 2 * 1024;               // 1,179,648 us
    ushort_t* w3p  = w2p + (size_t)9 * 256 * 2 * 256;            //   524,288 us
    ushort_t* wofp = w3p + (size_t)1024 * 2 * 256;               //    73,728 us

    // 1) pack weights
    {
        int total = 256 * 1024 + 256 * 256 * 9 + 1024 * 256 + 9 * 32 * 256;
        pack_weights_kernel<<<(total + 255) / 256, 256, 0, stream>>>(
            w1, w2, w3, w_off, w1p, w2p, w3p, wofp);
    }
    // 2) r = relu(w1 . x + b1)    M=256, K=1024  (M=128/block -> 392 blocks)
    {
        dim3 grid(HW / 64, CB / 128, N_);
        conv1x1_mfma_kernel<2, true, false><<<grid, 256, 0, stream>>>(
            w1p, x, b1, nullptr, r, CB, CIN);
    }
    // 3) off = conv3x3(r, w_off) + b_off   (MFMA, bf16 1-pass)
    {
        dim3 grid(H_, N_);
        offset_mfma_kernel<<<grid, 256, 0, stream>>>(r, wofp, b_off, offb);
    }
    // 4) r2 = relu(deform(r, off) . w2 + b2)
    {
        dim3 grid(H_, 2, N_);
        deform_mfma_kernel<<<grid, 512, 0, stream>>>(r, offb, w2p, b2, r2);
    }
    // 5) out = relu(x + w3 . r2 + b3)   M=1024, K=256  (M=128/block -> 1568 blocks)
    {
        dim3 grid(HW / 64, CIN / 128, N_);
        conv1x1_mfma_kernel<2, true, true><<<grid, 256, 0, stream>>>(
            w3p, r2, b3, x, out, CIN, CB);
    }
}

// Round 5
// 406.460 us; speedup vs baseline: 2.9903x; 1.0106x over previous
//
#include <hip/hip_runtime.h>
#include <hip/hip_bf16.h>

#define N_   4
#define CIN  1024
#define H_   56
#define W_   56
#define HW   3136
#define CB   256
#define KK   9
#define OFFC 18

typedef __attribute__((ext_vector_type(8))) short short8;
typedef __attribute__((ext_vector_type(4))) short short4v;
typedef __attribute__((ext_vector_type(4))) float float4v;
typedef unsigned short ushort_t;

// fp32 -> bf16 round-to-nearest-even
__device__ inline ushort_t bf16_rne(float f) {
    unsigned int u = __float_as_uint(f);
    unsigned int r = (u + 0x7FFFu + ((u >> 16) & 1u)) >> 16;
    return (ushort_t)r;
}
__device__ inline void split_bf16(float f, ushort_t& hi, ushort_t& lo) {
    ushort_t h = bf16_rne(f);
    float hf = __uint_as_float(((unsigned int)h) << 16);
    hi = h;
    lo = bf16_rne(f - hf);
}
__device__ inline short8 ld_frag_lds(const ushort_t* base) {
    short4v a = *(const short4v*)base;
    short4v b = *(const short4v*)(base + 4);
    return __builtin_shufflevector(a, b, 0, 1, 2, 3, 4, 5, 6, 7);
}

// ---------------------------------------------------------------------------
// Pack weights.
// w1 [256][1024]      -> w1p [o][2][1024]   (hi/lo)
// w2 [256][256][9]    -> w2p [k][o][256]    (hi only)
// w3 [1024][256]      -> w3p [o][2][256]    (hi/lo)
// w_off [18][256][9]  -> wofp [k][32][256]  (hi only, m padded 18->32)
// ---------------------------------------------------------------------------
__global__ void __launch_bounds__(256) pack_weights_kernel(
    const float* __restrict__ w1, const float* __restrict__ w2,
    const float* __restrict__ w3, const float* __restrict__ w_off,
    ushort_t* __restrict__ w1p, ushort_t* __restrict__ w2p,
    ushort_t* __restrict__ w3p, ushort_t* __restrict__ wofp)
{
    int e = blockIdx.x * 256 + threadIdx.x;
    if (e < 256 * 1024) {
        int o = e >> 10, k = e & 1023;
        ushort_t hi, lo; split_bf16(w1[e], hi, lo);
        w1p[(size_t)(o * 2 + 0) * 1024 + k] = hi;
        w1p[(size_t)(o * 2 + 1) * 1024 + k] = lo;
        return;
    }
    e -= 256 * 1024;
    if (e < 256 * 256 * 9) {
        int o = e / 2304; int rem = e % 2304; int c = rem / 9; int k = rem % 9;
        w2p[(size_t)(k * 256 + o) * 256 + c] = bf16_rne(w2[e]);
        return;
    }
    e -= 256 * 256 * 9;
    if (e < 1024 * 256) {
        int o = e >> 8, k = e & 255;
        ushort_t hi, lo; split_bf16(w3[e], hi, lo);
        w3p[(size_t)(o * 2 + 0) * 256 + k] = hi;
        w3p[(size_t)(o * 2 + 1) * 256 + k] = lo;
        return;
    }
    e -= 1024 * 256;
    if (e < 9 * 32 * 256) {
        int k = e / (32 * 256);
        int rem = e % (32 * 256);
        int m = rem >> 8, c = rem & 255;
        float v = (m < OFFC) ? w_off[((size_t)m * 256 + c) * 9 + k] : 0.f;
        wofp[e] = bf16_rne(v);
    }
}

// ---------------------------------------------------------------------------
// 1x1 conv via MFMA. A = weights (hi/lo, 2 passes), B = activations (bf16).
// ---------------------------------------------------------------------------
template <int MFRAG, bool RELU, bool RESID>
__global__ void __launch_bounds__(256, 4) conv1x1_mfma_kernel(
    const ushort_t* __restrict__ Wp,   // [M][2][Kdim]
    const float* __restrict__ Xin,     // [n][Kdim][HW]
    const float* __restrict__ bias,    // [M]
    const float* __restrict__ resid,   // [n][M][HW] or null
    float* __restrict__ Cout,          // [n][M][HW]
    int M, int Kdim)
{
    __shared__ ushort_t Bs[64][36];   // [p][k], pad 36

    const int tid  = threadIdx.x;
    const int wave = tid >> 6;
    const int lane = tid & 63;
    const int l15  = lane & 15;
    const int quad = lane >> 4;
    const int pBase = blockIdx.x * 64;
    const int mBase = blockIdx.y * (MFRAG * 64) + wave * (MFRAG * 16);
    const int n     = blockIdx.z;
    const float* Xn = Xin + (size_t)n * Kdim * HW;

    float4v acc[MFRAG][4];
#pragma unroll
    for (int i = 0; i < MFRAG; ++i)
#pragma unroll
        for (int j = 0; j < 4; ++j) acc[i][j] = (float4v)(0.f);

    const int kk = tid >> 3;          // 0..31
    const int pq = (tid & 7) * 8;     // 0..56

    for (int k0 = 0; k0 < Kdim; k0 += 32) {
        const float* src = &Xn[(size_t)(k0 + kk) * HW + pBase + pq];
        float4 v0 = *reinterpret_cast<const float4*>(src);
        float4 v1 = *reinterpret_cast<const float4*>(src + 4);
        __syncthreads();   // previous iter's Bs reads are done
        float vs[8] = {v0.x, v0.y, v0.z, v0.w, v1.x, v1.y, v1.z, v1.w};
#pragma unroll
        for (int j = 0; j < 8; ++j) Bs[pq + j][kk] = bf16_rne(vs[j]);
        __syncthreads();

        short8 ah[MFRAG], al[MFRAG];
#pragma unroll
        for (int mt = 0; mt < MFRAG; ++mt) {
            const ushort_t* arow = Wp +
                ((size_t)(mBase + mt * 16 + l15) * 2) * Kdim + k0 + quad * 8;
            ah[mt] = *(const short8*)(arow);
            al[mt] = *(const short8*)(arow + Kdim);
        }
        short8 bh[4];
#pragma unroll
        for (int nt = 0; nt < 4; ++nt)
            bh[nt] = ld_frag_lds(&Bs[nt * 16 + l15][quad * 8]);
#pragma unroll
        for (int mt = 0; mt < MFRAG; ++mt)
#pragma unroll
            for (int nt = 0; nt < 4; ++nt) {
                acc[mt][nt] = __builtin_amdgcn_mfma_f32_16x16x32_bf16(
                    ah[mt], bh[nt], acc[mt][nt], 0, 0, 0);
                acc[mt][nt] = __builtin_amdgcn_mfma_f32_16x16x32_bf16(
                    al[mt], bh[nt], acc[mt][nt], 0, 0, 0);
            }
    }

#pragma unroll
    for (int mt = 0; mt < MFRAG; ++mt)
#pragma unroll
        for (int rr = 0; rr < 4; ++rr) {
            int row = mBase + mt * 16 + quad * 4 + rr;
            float bv = bias[row];
#pragma unroll
            for (int nt = 0; nt < 4; ++nt) {
                int col = pBase + nt * 16 + l15;
                size_t idx = ((size_t)n * M + row) * HW + col;
                float v = acc[mt][nt][rr] + bv;
                if (RESID) v += resid[idx];
                if (RELU)  v = fmaxf(v, 0.f);
                Cout[idx] = v;
            }
        }
}

// ---------------------------------------------------------------------------
// Offset conv 3x3 via MFMA (bf16 1-pass), LDS row-window staging.
// ---------------------------------------------------------------------------
__global__ void __launch_bounds__(256, 2) offset_mfma_kernel(
    const float* __restrict__ r,        // [n][CB][HW]
    const ushort_t* __restrict__ wofp,  // [9][32][256] bf16
    const float* __restrict__ b_off,    // [18]
    float* __restrict__ off)            // [n][18][HW]
{
    __shared__ float win[32][174];      // 3 rows x 56 cols, padded stride

    const int tid  = threadIdx.x;
    const int h    = blockIdx.x;
    const int n    = blockIdx.y;
    const int wave = tid >> 6;
    const int lane = tid & 63;
    const int l15  = lane & 15;
    const int quad = lane >> 4;
    const float* rn = r + (size_t)n * CB * HW;

    const int p = wave * 16 + l15;      // output column this lane covers

    float4v acc[2];
    acc[0] = (float4v)(0.f);
    acc[1] = (float4v)(0.f);

    for (int cb = 0; cb < CB; cb += 32) {
        __syncthreads();
        for (int f = tid; f < 32 * 3 * 14; f += 256) {
            int c = f / 42, remf = f % 42, row = remf / 14, x4 = (remf % 14) * 4;
            int yg = h - 1 + row;
            float4 v = {0.f, 0.f, 0.f, 0.f};
            if (yg >= 0 && yg < H_)
                v = *reinterpret_cast<const float4*>(
                    &rn[(size_t)(cb + c) * HW + yg * W_ + x4]);
            *reinterpret_cast<float4*>(&win[c][row * 56 + x4]) = v;
        }
        __syncthreads();

#pragma unroll
        for (int k = 0; k < KK; ++k) {
            const int ky = k / 3;
            const int dx = (k % 3) - 1;
            int x = p + dx;
            bool pvalid = (p < 56) && (x >= 0) && (x < 56);
            int xc = min(max(x, 0), 55);
            short8 bh;
#pragma unroll
            for (int j = 0; j < 8; ++j) {
                float v = win[quad * 8 + j][ky * 56 + xc];
                bh[j] = (short)bf16_rne(pvalid ? v : 0.f);
            }
#pragma unroll
            for (int mt = 0; mt < 2; ++mt) {
                const ushort_t* arow = wofp +
                    (size_t)(k * 32 + mt * 16 + l15) * 256 + cb + quad * 8;
                short8 ah = *(const short8*)arow;
                acc[mt] = __builtin_amdgcn_mfma_f32_16x16x32_bf16(
                    ah, bh, acc[mt], 0, 0, 0);
            }
        }
    }

    if (p < 56) {
#pragma unroll
        for (int mt = 0; mt < 2; ++mt)
#pragma unroll
            for (int rr = 0; rr < 4; ++rr) {
                int m = mt * 16 + quad * 4 + rr;
                if (m < OFFC)
                    off[((size_t)n * OFFC + m) * HW + h * W_ + p] =
                        acc[mt][rr] + b_off[m];
            }
    }
}

// ---------------------------------------------------------------------------
// Deformable conv via MFMA. 512 thr = 8 waves; M=256 (wave: 32 m),
// N-tile 32 (28 real positions = x-half of one row).
// Per cb-chunk of 32 channels: stage window once, build ALL 9 taps' B tiles
// in one phase, then 36 MFMAs + 18 A-loads with no intervening barriers.
// A = w2 hi-plane only (single pass). Grid: (56 h, 2 xhalf, 4 n).
// ---------------------------------------------------------------------------
#define TPX   28
#define WROWS 5
#define WCOLS 36
#define WPOS  (WROWS * WCOLS)   // 180
#define CSTR  33

__global__ void __launch_bounds__(512, 2) deform_mfma_kernel(
    const float* __restrict__ r,      // [n][CB][HW]
    const float* __restrict__ off,    // [n][18][HW]
    const ushort_t* __restrict__ w2p, // [9][256][256] bf16 hi
    const float* __restrict__ b2,
    float* __restrict__ r2)           // [n][CB][HW]
{
    __shared__ float    win[WPOS][CSTR];        // 23760 B
    __shared__ ushort_t Bs[KK][32][36];         // 20736 B
    __shared__ short    widx[KK][TPX][4];       // 2016 B
    __shared__ float    wwgt[KK][TPX][4];       // 4032 B
    __shared__ unsigned char fastf[KK][TPX];    // 252 B

    const int tid = threadIdx.x;
    const int h   = blockIdx.x;
    const int xb  = blockIdx.y * TPX;
    const int n   = blockIdx.z;
    const float* rn   = r + (size_t)n * CB * HW;
    const float* offn = off + (size_t)n * OFFC * HW;

    // ---- per-(tap, position) bilinear metadata, window-relative ----
    for (int e = tid; e < KK * TPX; e += 512) {
        int k = e / TPX, p = e % TPX;
        int pg = xb + p;
        float dy = offn[(size_t)(2 * k) * HW + h * W_ + pg];
        float dx = offn[(size_t)(2 * k + 1) * HW + h * W_ + pg];
        float ys = (float)(h + (k / 3) - 1) + dy;
        float xs = (float)(pg + (k % 3) - 1) + dx;
        float y0f = floorf(ys), x0f = floorf(xs);
        int y0 = (int)y0f, x0 = (int)x0f;
        float wy1 = ys - y0f, wy0 = 1.f - wy1;
        float wx1 = xs - x0f, wx0 = 1.f - wx1;
        bool fast = true;
#pragma unroll
        for (int u = 0; u < 2; ++u)
#pragma unroll
            for (int vv = 0; vv < 2; ++vv) {
                int yy = y0 + u, xx = x0 + vv;
                bool valid = (yy >= 0) && (yy <= 55) && (xx >= 0) && (xx <= 55);
                float wgt = valid ? (u ? wy1 : wy0) * (vv ? wx1 : wx0) : 0.f;
                int ry = yy - (h - 2);
                int rx = xx - (xb - 4);
                if (wgt != 0.f &&
                    (ry < 0 || ry >= WROWS || rx < 0 || rx >= WCOLS))
                    fast = false;
                int ryc = min(max(ry, 0), WROWS - 1);
                int rxc = min(max(rx, 0), WCOLS - 1);
                widx[k][p][u * 2 + vv] = (short)(ryc * WCOLS + rxc);
                wwgt[k][p][u * 2 + vv] = wgt;
            }
        fastf[k][p] = fast ? 1 : 0;
    }

    const int wave = tid >> 6;     // 0..7
    const int lane = tid & 63;
    const int l15  = lane & 15;
    const int quad = lane >> 4;
    const int mW   = wave * 32;

    float4v acc[2][2];
#pragma unroll
    for (int i = 0; i < 2; ++i)
#pragma unroll
        for (int j = 0; j < 2; ++j) acc[i][j] = (float4v)(0.f);

    for (int cb = 0; cb < CB; cb += 32) {
        __syncthreads();  // prev MFMA Bs-reads done; metadata visible (1st it)
        // ---- stage window: 32 ch x 5 rows x 36 cols (x in [xb-4, xb+32)) ----
        for (int f = tid; f < 32 * WROWS * 9; f += 512) {
            int c = f / 45, remf = f % 45, row = remf / 9, q = remf % 9;
            int yg = min(max(h - 2 + row, 0), H_ - 1);
            int xg = xb - 4 + q * 4;
            const float* src = &rn[(size_t)(cb + c) * HW + yg * W_];
            float vx[4];
            if (xg >= 0 && xg <= W_ - 4) {
                float4 v = *reinterpret_cast<const float4*>(src + xg);
                vx[0] = v.x; vx[1] = v.y; vx[2] = v.z; vx[3] = v.w;
            } else {
#pragma unroll
                for (int j = 0; j < 4; ++j)
                    vx[j] = src[min(max(xg + j, 0), W_ - 1)];
            }
            int pos = row * WCOLS + q * 4;
#pragma unroll
            for (int j = 0; j < 4; ++j) win[pos + j][c] = vx[j];
        }
        __syncthreads();

        // ---- build B tiles for ALL 9 taps: 9 x 32 ch x 32 p ----
#pragma unroll
        for (int ii = 0; ii < 18; ++ii) {
            int e = tid + 512 * ii;          // < 9216
            int k = e >> 10;
            int rem = e & 1023;
            int p = rem >> 5;
            int c = rem & 31;
            float sv = 0.f;
            if (p < TPX) {
                if (fastf[k][p]) {
                    short4v id4 = *(const short4v*)&widx[k][p][0];
                    float4 w4 = *reinterpret_cast<const float4*>(&wwgt[k][p][0]);
                    sv = w4.x * win[id4.x][c] + w4.y * win[id4.y][c] +
                         w4.z * win[id4.z][c] + w4.w * win[id4.w][c];
                } else {
                    int pg = xb + p;
                    float dy = offn[(size_t)(2 * k) * HW + h * W_ + pg];
                    float dx = offn[(size_t)(2 * k + 1) * HW + h * W_ + pg];
                    float ys = (float)(h + (k / 3) - 1) + dy;
                    float xs = (float)(pg + (k % 3) - 1) + dx;
                    float y0f = floorf(ys), x0f = floorf(xs);
                    int y0 = (int)y0f, x0 = (int)x0f;
                    float wy1 = ys - y0f, wy0 = 1.f - wy1;
                    float wx1 = xs - x0f, wx0 = 1.f - wx1;
                    const float* rc = rn + (size_t)(cb + c) * HW;
#pragma unroll
                    for (int u = 0; u < 2; ++u)
#pragma unroll
                        for (int vv = 0; vv < 2; ++vv) {
                            int yy = y0 + u, xx = x0 + vv;
                            if (yy >= 0 && yy <= 55 && xx >= 0 && xx <= 55) {
                                float wgt = (u ? wy1 : wy0) * (vv ? wx1 : wx0);
                                sv += wgt * rc[yy * W_ + xx];
                            }
                        }
                }
            }
            Bs[k][p][c] = bf16_rne(sv);
        }
        __syncthreads();

        // ---- MFMA over all 9 taps, no barriers between ----
#pragma unroll
        for (int k = 0; k < KK; ++k) {
            short8 ah[2];
#pragma unroll
            for (int mt = 0; mt < 2; ++mt) {
                const ushort_t* arow = w2p +
                    (size_t)(k * 256 + (mW + mt * 16 + l15)) * 256 +
                    cb + quad * 8;
                ah[mt] = *(const short8*)(arow);
            }
            short8 bh[2];
#pragma unroll
            for (int nt = 0; nt < 2; ++nt)
                bh[nt] = ld_frag_lds(&Bs[k][nt * 16 + l15][quad * 8]);
#pragma unroll
            for (int mt = 0; mt < 2; ++mt)
#pragma unroll
                for (int nt = 0; nt < 2; ++nt)
                    acc[mt][nt] = __builtin_amdgcn_mfma_f32_16x16x32_bf16(
                        ah[mt], bh[nt], acc[mt][nt], 0, 0, 0);
        }
    }

    // ---- epilogue: bias + relu ----
#pragma unroll
    for (int mt = 0; mt < 2; ++mt)
#pragma unroll
        for (int rr = 0; rr < 4; ++rr) {
            int o = mW + mt * 16 + quad * 4 + rr;
            float bv = b2[o];
#pragma unroll
            for (int nt = 0; nt < 2; ++nt) {
                int p = nt * 16 + l15;
                if (p < TPX) {
                    float v = fmaxf(acc[mt][nt][rr] + bv, 0.f);
                    r2[((size_t)n * CB + o) * HW + h * W_ + xb + p] = v;
                }
            }
        }
}

// ---------------------------------------------------------------------------
// kernel_launch
// ---------------------------------------------------------------------------
extern "C" void kernel_launch(void* const* d_in, const int* in_sizes, int n_in,
                              void* d_out, int out_size, void* d_ws, size_t ws_size,
                              hipStream_t stream)
{
    const float* x     = (const float*)d_in[0];
    const float* w1    = (const float*)d_in[1];
    const float* b1    = (const float*)d_in[2];
    const float* w_off = (const float*)d_in[3];
    const float* b_off = (const float*)d_in[4];
    const float* w2    = (const float*)d_in[5];
    const float* b2    = (const float*)d_in[6];
    const float* w3    = (const float*)d_in[7];
    const float* b3    = (const float*)d_in[8];
    float* out = (float*)d_out;

    float* ws  = (float*)d_ws;
    float* r    = ws;                             // 3,211,264 f
    float* r2   = r  + (size_t)N_ * CB * HW;      // 3,211,264 f
    float* offb = r2 + (size_t)N_ * CB * HW;      //   225,792 f
    ushort_t* w1p  = (ushort_t*)(offb + (size_t)N_ * OFFC * HW); // 524,288 us
    ushort_t* w2p  = w1p + (size_t)256 * 2 * 1024;               //   589,824 us
    ushort_t* w3p  = w2p + (size_t)9 * 256 * 256;                //   524,288 us
    ushort_t* wofp = w3p + (size_t)1024 * 2 * 256;               //    73,728 us

    // 1) pack weights
    {
        int total = 256 * 1024 + 256 * 256 * 9 + 1024 * 256 + 9 * 32 * 256;
        pack_weights_kernel<<<(total + 255) / 256, 256, 0, stream>>>(
            w1, w2, w3, w_off, w1p, w2p, w3p, wofp);
    }
    // 2) r = relu(w1 . x + b1)    M=256, K=1024
    {
        dim3 grid(HW / 64, CB / 128, N_);
        conv1x1_mfma_kernel<2, true, false><<<grid, 256, 0, stream>>>(
            w1p, x, b1, nullptr, r, CB, CIN);
    }
    // 3) off = conv3x3(r, w_off) + b_off
    {
        dim3 grid(H_, N_);
        offset_mfma_kernel<<<grid, 256, 0, stream>>>(r, wofp, b_off, offb);
    }
    // 4) r2 = relu(deform(r, off) . w2 + b2)
    {
        dim3 grid(H_, 2, N_);
        deform_mfma_kernel<<<grid, 512, 0, stream>>>(r, offb, w2p, b2, r2);
    }
    // 5) out = relu(x + w3 . r2 + b3)   M=1024, K=256
    {
        dim3 grid(HW / 64, CIN / 128, N_);
        conv1x1_mfma_kernel<2, true, true><<<grid, 256, 0, stream>>>(
            w3p, r2, b3, x, out, CIN, CB);
    }
}